// Round 1
// baseline (737.599 us; speedup 1.0000x reference)
//
#include <hip/hip_runtime.h>
#include <hip/hip_bf16.h>
#include <cstdint>
#include <cstddef>

// ---------- types / helpers ----------
typedef __bf16  bf16x8  __attribute__((ext_vector_type(8)));
typedef float   f32x4   __attribute__((ext_vector_type(4)));
typedef ushort  ushort8 __attribute__((ext_vector_type(8)));

#define ASYNC16(gp, lp)                                                        \
  __builtin_amdgcn_global_load_lds(                                            \
      (const __attribute__((address_space(1))) void*)(gp),                     \
      (__attribute__((address_space(3))) void*)(lp), 16, 0, 0)

__device__ __forceinline__ ushort f2bf(float f) {
  __hip_bfloat16 h = __float2bfloat16(f);   // RNE
  ushort u; __builtin_memcpy(&u, &h, 2); return u;
}

#define SINF (-1e30f)

// ---------- f32 -> bf16 bulk convert (vectorized, grid-stride) ----------
__global__ __launch_bounds__(256) void to_bf16(
    const float* __restrict__ src, ushort* __restrict__ dst, int n8) {
  int i = blockIdx.x * 256 + threadIdx.x;
  const int stride = gridDim.x * 256;
  for (; i < n8; i += stride) {
    const float4* s = (const float4*)(src + (size_t)i * 8);
    float4 a0 = s[0], a1 = s[1];
    ushort8 u = { f2bf(a0.x), f2bf(a0.y), f2bf(a0.z), f2bf(a0.w),
                  f2bf(a1.x), f2bf(a1.y), f2bf(a1.z), f2bf(a1.w) };
    *(ushort8*)&dst[(size_t)i * 8] = u;
  }
}

// ---------- weight transpose+convert: Wt[n][k] = bf16(W[k][n]) ----------
__global__ __launch_bounds__(256) void transpose_w(
    const float* __restrict__ W0, const float* __restrict__ W1,
    const float* __restrict__ W2, const float* __restrict__ W3,
    ushort* __restrict__ out) {
  __shared__ float tile[32][33];
  const float* W = blockIdx.z == 0 ? W0 : blockIdx.z == 1 ? W1
                 : blockIdx.z == 2 ? W2 : W3;
  ushort* T = out + (size_t)blockIdx.z * (1024u * 1024u);
  const int n0 = blockIdx.x * 32, k0 = blockIdx.y * 32;
  const int t = threadIdx.x;
  const int r = t >> 3, c = (t & 7) * 4;
  float4 v = *(const float4*)&W[(size_t)(k0 + r) * 1024 + n0 + c];
  tile[r][c + 0] = v.x; tile[r][c + 1] = v.y;
  tile[r][c + 2] = v.z; tile[r][c + 3] = v.w;
  __syncthreads();
  ushort4 o;
  o.x = f2bf(tile[c + 0][r]); o.y = f2bf(tile[c + 1][r]);
  o.z = f2bf(tile[c + 2][r]); o.w = f2bf(tile[c + 3][r]);
  *(ushort4*)&T[(size_t)(n0 + r) * 1024 + k0 + c] = o;
}

// ---------- V transpose per (b,h): v_t[bh][dh][s] = v_s[b*1500+s][h*64+dh] ----
// v_t row stride 1536 (16B-aligned rows, zero-padded s>=1500).
__global__ __launch_bounds__(256) void transpose_v(
    const ushort* __restrict__ v_s, ushort* __restrict__ v_t) {
  __shared__ ushort tile[32][36];
  const int bh = blockIdx.z;            // 0..127
  const int b = bh >> 4, h = bh & 15;
  const int d0 = blockIdx.y * 32;       // 0 or 32
  const int s0 = blockIdx.x * 32;       // 0..1504 step 32
  const int t = threadIdx.x;
  const int r = t >> 3, c4 = (t & 7) * 4;
  const int s = s0 + r;
  ushort4 v = {0, 0, 0, 0};
  if (s < 1500)
    v = *(const ushort4*)&v_s[(size_t)(b * 1500 + s) * 1024 + h * 64 + d0 + c4];
  tile[r][c4 + 0] = v.x; tile[r][c4 + 1] = v.y;
  tile[r][c4 + 2] = v.z; tile[r][c4 + 3] = v.w;
  __syncthreads();
  ushort4 o;
  o.x = tile[c4 + 0][r]; o.y = tile[c4 + 1][r];
  o.z = tile[c4 + 2][r]; o.w = tile[c4 + 3][r];
  *(ushort4*)&v_t[((size_t)bh * 64 + d0 + r) * 1536 + s0 + c4] = o;
}

// ---------- GEMM  C[M,1024] = (A[M,1024] @ Bt^T + bias) * scale ----------
// Bt is bf16 [N=1024][K=1024]. A is f32 (A_F32) or bf16. C is f32 or bf16.
// m97 structure: 128x128 tile, BK=32, 4 waves of 64x64, 16x16x32 bf16 MFMA.
template <bool A_F32, bool C_F32>
__global__ __launch_bounds__(256) void gemm_bt(
    const void* __restrict__ Ap, const ushort* __restrict__ Bt,
    const float* __restrict__ bias, void* __restrict__ Cp,
    int M, float scale) {
  __shared__ ushort As[128 * 32];
  __shared__ ushort Bs[128 * 32];
  const int tid  = threadIdx.x;
  const int lane = tid & 63, w = tid >> 6;
  const int m15  = lane & 15, q4 = lane >> 4;
  const int wm   = w >> 1,  wn = w & 1;
  const int m0 = blockIdx.x * 128, n0 = blockIdx.y * 128;
  const int sr = lane >> 2;          // staging row within 16-row slab
  const int sc = (lane & 3) * 8;     // staging col (8 bf16 = 16B)
  f32x4 acc[4][4] = {};
  for (int k0 = 0; k0 < 1024; k0 += 32) {
    __syncthreads();
    // --- B staging: async 16B direct-to-LDS ---
    #pragma unroll
    for (int j = 0; j < 2; ++j) {
      int n = w * 2 + j;             // slab id 0..7
      int r = n * 16 + sr;           // tile row 0..127
      ASYNC16(&Bt[(size_t)(n0 + r) * 1024 + k0 + sc], &Bs[n * 512]);
    }
    // --- A staging ---
    if constexpr (A_F32) {
      const float* Af = (const float*)Ap;
      #pragma unroll
      for (int h = 0; h < 2; ++h) {
        int g = tid + h * 256;       // group 0..511
        int row = g >> 2, kg = g & 3;
        int ga = min(m0 + row, M - 1);
        const float* src = &Af[(size_t)ga * 1024 + k0 + kg * 8];
        float4 a0 = *(const float4*)src;
        float4 a1 = *(const float4*)(src + 4);
        ushort8 u = { f2bf(a0.x), f2bf(a0.y), f2bf(a0.z), f2bf(a0.w),
                      f2bf(a1.x), f2bf(a1.y), f2bf(a1.z), f2bf(a1.w) };
        *(ushort8*)&As[row * 32 + kg * 8] = u;
      }
    } else {
      const ushort* Ab = (const ushort*)Ap;
      #pragma unroll
      for (int j = 0; j < 2; ++j) {
        int n = w * 2 + j;
        int r = n * 16 + sr;
        int ga = min(m0 + r, M - 1);
        ASYNC16(&Ab[(size_t)ga * 1024 + k0 + sc], &As[n * 512]);
      }
    }
    __syncthreads();
    bf16x8 af[4], bfr[4];
    #pragma unroll
    for (int i = 0; i < 4; ++i)
      af[i] = *(const bf16x8*)&As[(wm * 64 + i * 16 + m15) * 32 + q4 * 8];
    #pragma unroll
    for (int i = 0; i < 4; ++i)
      bfr[i] = *(const bf16x8*)&Bs[(wn * 64 + i * 16 + m15) * 32 + q4 * 8];
    #pragma unroll
    for (int i = 0; i < 4; ++i)
      #pragma unroll
      for (int j = 0; j < 4; ++j)
        acc[i][j] = __builtin_amdgcn_mfma_f32_16x16x32_bf16(af[i], bfr[j],
                                                            acc[i][j], 0, 0, 0);
  }
  // epilogue: C/D layout col=lane&15, row=(lane>>4)*4+reg
  #pragma unroll
  for (int j = 0; j < 4; ++j) {
    int col = n0 + wn * 64 + j * 16 + m15;
    float bb = bias ? bias[col] : 0.f;
    #pragma unroll
    for (int i = 0; i < 4; ++i) {
      #pragma unroll
      for (int r = 0; r < 4; ++r) {
        int row = m0 + wm * 64 + i * 16 + q4 * 4 + r;
        if (row < M) {
          float v = (acc[i][j][r] + bb) * scale;
          if constexpr (C_F32)
            ((float*)Cp)[(size_t)row * 1024 + col] = v;
          else
            ((ushort*)Cp)[(size_t)row * 1024 + col] = f2bf(v);
        }
      }
    }
  }
}

// ---------- fused attention ----------
// grid (7, 16, 8): 64 Q-rows per block, per (b,h). Writes qk logits (f32) and
// wv = softmax(qk) @ V (bf16, into ws). q/k pre-scaled by Dh^-0.25 at GEMM.
// K tile LDS is XOR-swizzled (source-side pre-swizzle, read-side XOR): kills
// the 16-way bank conflict of the linear 128B-stride layout.
// V fragments are read directly from global v_t (L2/L3-resident, 64B segments)
// -- no LDS staging, no per-chunk transpose.
__global__ __launch_bounds__(256) void attn(
    const ushort* __restrict__ q_s, const ushort* __restrict__ k_s,
    const ushort* __restrict__ v_t, float* __restrict__ qk_out,
    ushort* __restrict__ wv) {
  __shared__ ushort Kb[64 * 64];        // K chunk [s][d], XOR-swizzled
  __shared__ ushort Pw[4][16 * 72];     // per-wave P tile [t][s], pad 72
  const int tid  = threadIdx.x;
  const int lane = tid & 63, w = tid >> 6;
  const int m15  = lane & 15, q4 = lane >> 4;
  const int h = blockIdx.y, b = blockIdx.z;
  const int t0 = blockIdx.x * 64;
  const int trow = t0 + w * 16;         // this wave's 16-row Q band
  // Q fragments held in registers for the whole block (A-layout: m=lane&15)
  const ushort* qrow = &q_s[(size_t)(b * 448 + trow + m15) * 1024 + h * 64];
  bf16x8 qf0 = *(const bf16x8*)&qrow[q4 * 8];
  bf16x8 qf1 = *(const bf16x8*)&qrow[32 + q4 * 8];
  f32x4 o[4] = {};
  float m_r[4] = {SINF, SINF, SINF, SINF};
  float l_r[4] = {0.f, 0.f, 0.f, 0.f};
  const int krb = lane >> 3;                       // staging row-in-slab 0..7
  const int kc_sw = (((lane & 7) ^ krb) * 8);      // pre-swizzled source col
  // V fragment base: row dh = d*16 + m15 of v_t[bh], col chunk q4*8
  const ushort* vbase =
      &v_t[((size_t)(b * 16 + h) * 64 + m15) * 1536 + q4 * 8];
  for (int s0 = 0; s0 < 1500; s0 += 64) {
    __syncthreads();                    // protect Kb reuse
    // stage K chunk (rows clamped; masked at softmax). Linear LDS dest +
    // inverse-swizzled global source column (rule #21).
    #pragma unroll
    for (int j = 0; j < 2; ++j) {
      int n = w * 2 + j;
      int sg = min(s0 + n * 8 + krb, 1499);
      ASYNC16(&k_s[(size_t)(b * 1500 + sg) * 1024 + h * 64 + kc_sw],
              &Kb[n * 512]);
    }
    __syncthreads();
    // QK^T: 4 s-col tiles x 2 k-steps, swizzled reads (2-way max -> free)
    f32x4 lg[4];
    #pragma unroll
    for (int scol = 0; scol < 4; ++scol) {
      const int r = scol * 16 + m15;
      const int sw = (m15 & 7) * 8;
      bf16x8 kf0 = *(const bf16x8*)&Kb[r * 64 + ((q4 * 8) ^ sw)];
      bf16x8 kf1 = *(const bf16x8*)&Kb[r * 64 + ((32 + q4 * 8) ^ sw)];
      f32x4 a = {};
      a = __builtin_amdgcn_mfma_f32_16x16x32_bf16(qf0, kf0, a, 0, 0, 0);
      a = __builtin_amdgcn_mfma_f32_16x16x32_bf16(qf1, kf1, a, 0, 0, 0);
      lg[scol] = a;
    }
    // chunk row-max (16 lanes sharing q4 hold one row's 16 s-values)
    float mc[4] = {SINF, SINF, SINF, SINF};
    #pragma unroll
    for (int scol = 0; scol < 4; ++scol) {
      bool valid = (s0 + scol * 16 + m15) < 1500;
      #pragma unroll
      for (int r = 0; r < 4; ++r)
        mc[r] = fmaxf(mc[r], valid ? lg[scol][r] : SINF);
    }
    #pragma unroll
    for (int off = 1; off < 16; off <<= 1)
      #pragma unroll
      for (int r = 0; r < 4; ++r)
        mc[r] = fmaxf(mc[r], __shfl_xor(mc[r], off));
    // online-softmax rescale
    #pragma unroll
    for (int r = 0; r < 4; ++r) {
      float mn = fmaxf(m_r[r], mc[r]);
      float alpha = __expf(m_r[r] - mn);   // first chunk: exp(-1e30)=0, no NaN
      l_r[r] *= alpha;
      #pragma unroll
      for (int d = 0; d < 4; ++d) o[d][r] *= alpha;
      m_r[r] = mn;
    }
    // P = exp(l - m), qk logit store (f32), row-sum
    float psum[4] = {0.f, 0.f, 0.f, 0.f};
    #pragma unroll
    for (int scol = 0; scol < 4; ++scol) {
      int sg = s0 + scol * 16 + m15;
      bool valid = sg < 1500;
      #pragma unroll
      for (int r = 0; r < 4; ++r) {
        float lv = lg[scol][r];
        float p = valid ? __expf(lv - m_r[r]) : 0.f;
        psum[r] += p;
        Pw[w][(q4 * 4 + r) * 72 + scol * 16 + m15] = f2bf(p);
        if (valid)
          qk_out[(size_t)((b * 16 + h) * 448 + trow + q4 * 4 + r) * 1500 + sg]
              = lv;
      }
    }
    #pragma unroll
    for (int off = 1; off < 16; off <<= 1)
      #pragma unroll
      for (int r = 0; r < 4; ++r)
        psum[r] += __shfl_xor(psum[r], off);
    #pragma unroll
    for (int r = 0; r < 4; ++r) l_r[r] += psum[r];
    // PV: P (A-layout via same-wave LDS round trip) x V^T fragments straight
    // from global v_t (per-(b,h) slice is 187.5 KB -> L2/L3-resident; each
    // instruction reads 16 rows x 64B contiguous segments).
    #pragma unroll
    for (int ks = 0; ks < 2; ++ks) {
      bf16x8 vf[4];
      #pragma unroll
      for (int d = 0; d < 4; ++d)
        vf[d] = *(const bf16x8*)&vbase[(size_t)(d * 16) * 1536 + s0 + ks * 32];
      bf16x8 pf = *(const bf16x8*)&Pw[w][m15 * 72 + ks * 32 + q4 * 8];
      #pragma unroll
      for (int d = 0; d < 4; ++d)
        o[d] = __builtin_amdgcn_mfma_f32_16x16x32_bf16(pf, vf[d], o[d], 0, 0, 0);
    }
  }
  // normalize + store wv (bf16 workspace)
  #pragma unroll
  for (int d = 0; d < 4; ++d)
    #pragma unroll
    for (int r = 0; r < 4; ++r) {
      float val = o[d][r] / l_r[r];
      wv[(size_t)(b * 448 + trow + q4 * 4 + r) * 1024 + h * 64 + d * 16 + m15]
          = f2bf(val);
    }
}

// ---------- launch ----------
extern "C" void kernel_launch(void* const* d_in, const int* in_sizes, int n_in,
                              void* d_out, int out_size, void* d_ws,
                              size_t ws_size, hipStream_t stream) {
  const float* x  = (const float*)d_in[0];   // [8,448,1024] f32
  const float* xa = (const float*)d_in[1];   // [8,1500,1024] f32
  const float* Wq = (const float*)d_in[2];
  const float* bq = (const float*)d_in[3];
  const float* Wk = (const float*)d_in[4];
  const float* Wv = (const float*)d_in[5];
  const float* bv = (const float*)d_in[6];
  const float* Wo = (const float*)d_in[7];
  const float* bo = (const float*)d_in[8];
  float* out = (float*)d_out;                        // [8,448,1024] f32
  float* qk  = out + (size_t)8 * 448 * 1024;         // [8,16,448,1500] f32
  char* ws = (char*)d_ws;
  ushort* Wt    = (ushort*)ws;                               // 4x 1M bf16 (8 MB)
  ushort* q_s   = (ushort*)(ws + (size_t)8   * 1024 * 1024); // 3584x1024 bf16
  ushort* k_s   = (ushort*)(ws + (size_t)16  * 1024 * 1024); // 12000x1024 bf16
  ushort* v_s   = (ushort*)(ws + (size_t)42  * 1024 * 1024); // 12000x1024 bf16
  ushort* wv_s  = (ushort*)(ws + (size_t)68  * 1024 * 1024); // 3584x1024 bf16
  ushort* x_bf  = (ushort*)(ws + (size_t)76  * 1024 * 1024); // 3584x1024 bf16
  ushort* xa_bf = (ushort*)(ws + (size_t)84  * 1024 * 1024); // 12000x1024 bf16
  ushort* v_t   = (ushort*)(ws + (size_t)112 * 1024 * 1024); // 128x64x1536 bf16

  to_bf16<<<dim3(1792), 256, 0, stream>>>(x,  x_bf,  458752);
  to_bf16<<<dim3(2048), 256, 0, stream>>>(xa, xa_bf, 1536000);
  transpose_w<<<dim3(32, 32, 4), 256, 0, stream>>>(Wq, Wk, Wv, Wo, Wt);
  const float sc = 0.35355339059327373f;  // 64^-0.25
  gemm_bt<false, false><<<dim3(28, 8), 256, 0, stream>>>(x_bf,  Wt,               bq,      q_s, 3584,  sc);
  gemm_bt<false, false><<<dim3(94, 8), 256, 0, stream>>>(xa_bf, Wt + 1u*1048576u, nullptr, k_s, 12000, sc);
  gemm_bt<false, false><<<dim3(94, 8), 256, 0, stream>>>(xa_bf, Wt + 2u*1048576u, bv,      v_s, 12000, 1.0f);
  transpose_v<<<dim3(48, 2, 128), 256, 0, stream>>>(v_s, v_t);
  attn<<<dim3(7, 16, 8), 256, 0, stream>>>(q_s, k_s, v_t, qk, wv_s);
  gemm_bt<false, true ><<<dim3(28, 8), 256, 0, stream>>>(wv_s, Wt + 3u*1048576u, bo,      out, 3584,  1.0f);
}

// Round 2
// 718.500 us; speedup vs baseline: 1.0266x; 1.0266x over previous
//
#include <hip/hip_runtime.h>
#include <hip/hip_bf16.h>
#include <cstdint>
#include <cstddef>

// ---------- types / helpers ----------
typedef __bf16  bf16x8  __attribute__((ext_vector_type(8)));
typedef float   f32x4   __attribute__((ext_vector_type(4)));
typedef ushort  ushort8 __attribute__((ext_vector_type(8)));

#define ASYNC16(gp, lp)                                                        \
  __builtin_amdgcn_global_load_lds(                                            \
      (const __attribute__((address_space(1))) void*)(gp),                     \
      (__attribute__((address_space(3))) void*)(lp), 16, 0, 0)

__device__ __forceinline__ ushort f2bf(float f) {
  __hip_bfloat16 h = __float2bfloat16(f);   // RNE
  ushort u; __builtin_memcpy(&u, &h, 2); return u;
}

#define SINF (-1e30f)

// ---------- f32 -> bf16 bulk convert (vectorized, grid-stride) ----------
__global__ __launch_bounds__(256) void to_bf16(
    const float* __restrict__ src, ushort* __restrict__ dst, int n8) {
  int i = blockIdx.x * 256 + threadIdx.x;
  const int stride = gridDim.x * 256;
  for (; i < n8; i += stride) {
    const float4* s = (const float4*)(src + (size_t)i * 8);
    float4 a0 = s[0], a1 = s[1];
    ushort8 u = { f2bf(a0.x), f2bf(a0.y), f2bf(a0.z), f2bf(a0.w),
                  f2bf(a1.x), f2bf(a1.y), f2bf(a1.z), f2bf(a1.w) };
    *(ushort8*)&dst[(size_t)i * 8] = u;
  }
}

// ---------- weight transpose+convert: Wt[n][k] = bf16(W[k][n]) ----------
__global__ __launch_bounds__(256) void transpose_w(
    const float* __restrict__ W0, const float* __restrict__ W1,
    const float* __restrict__ W2, const float* __restrict__ W3,
    ushort* __restrict__ out) {
  __shared__ float tile[32][33];
  const float* W = blockIdx.z == 0 ? W0 : blockIdx.z == 1 ? W1
                 : blockIdx.z == 2 ? W2 : W3;
  ushort* T = out + (size_t)blockIdx.z * (1024u * 1024u);
  const int n0 = blockIdx.x * 32, k0 = blockIdx.y * 32;
  const int t = threadIdx.x;
  const int r = t >> 3, c = (t & 7) * 4;
  float4 v = *(const float4*)&W[(size_t)(k0 + r) * 1024 + n0 + c];
  tile[r][c + 0] = v.x; tile[r][c + 1] = v.y;
  tile[r][c + 2] = v.z; tile[r][c + 3] = v.w;
  __syncthreads();
  ushort4 o;
  o.x = f2bf(tile[c + 0][r]); o.y = f2bf(tile[c + 1][r]);
  o.z = f2bf(tile[c + 2][r]); o.w = f2bf(tile[c + 3][r]);
  *(ushort4*)&T[(size_t)(n0 + r) * 1024 + k0 + c] = o;
}

// ---------- V transpose per (b,h): v_t[bh][dh][s] = v_s[b*1500+s][h*64+dh] ----
// row stride 1600 (pad past 1500 zeroed; PV tail reads stay in-row).
__global__ __launch_bounds__(256) void transpose_v(
    const ushort* __restrict__ v_s, ushort* __restrict__ v_t) {
  __shared__ ushort tile[32][36];
  const int bh = blockIdx.z;            // 0..127
  const int b = bh >> 4, h = bh & 15;
  const int d0 = blockIdx.y * 32;       // 0 or 32
  const int s0 = blockIdx.x * 32;       // 0..1568 step 32
  const int t = threadIdx.x;
  const int r = t >> 3, c4 = (t & 7) * 4;
  const int s = s0 + r;
  ushort4 v = {0, 0, 0, 0};
  if (s < 1500)
    v = *(const ushort4*)&v_s[(size_t)(b * 1500 + s) * 1024 + h * 64 + d0 + c4];
  tile[r][c4 + 0] = v.x; tile[r][c4 + 1] = v.y;
  tile[r][c4 + 2] = v.z; tile[r][c4 + 3] = v.w;
  __syncthreads();
  ushort4 o;
  o.x = tile[c4 + 0][r]; o.y = tile[c4 + 1][r];
  o.z = tile[c4 + 2][r]; o.w = tile[c4 + 3][r];
  *(ushort4*)&v_t[((size_t)bh * 64 + d0 + r) * 1600 + s0 + c4] = o;
}

// ---------- GEMM  C[M,1024] = (A[M,1024] @ Bt^T + bias) * scale ----------
template <bool A_F32, bool C_F32>
__global__ __launch_bounds__(256) void gemm_bt(
    const void* __restrict__ Ap, const ushort* __restrict__ Bt,
    const float* __restrict__ bias, void* __restrict__ Cp,
    int M, float scale) {
  __shared__ ushort As[128 * 32];
  __shared__ ushort Bs[128 * 32];
  const int tid  = threadIdx.x;
  const int lane = tid & 63, w = tid >> 6;
  const int m15  = lane & 15, q4 = lane >> 4;
  const int wm   = w >> 1,  wn = w & 1;
  const int m0 = blockIdx.x * 128, n0 = blockIdx.y * 128;
  const int sr = lane >> 2;
  const int sc = (lane & 3) * 8;
  f32x4 acc[4][4] = {};
  for (int k0 = 0; k0 < 1024; k0 += 32) {
    __syncthreads();
    #pragma unroll
    for (int j = 0; j < 2; ++j) {
      int n = w * 2 + j;
      int r = n * 16 + sr;
      ASYNC16(&Bt[(size_t)(n0 + r) * 1024 + k0 + sc], &Bs[n * 512]);
    }
    if constexpr (A_F32) {
      const float* Af = (const float*)Ap;
      #pragma unroll
      for (int hh = 0; hh < 2; ++hh) {
        int g = tid + hh * 256;
        int row = g >> 2, kg = g & 3;
        int ga = min(m0 + row, M - 1);
        const float* src = &Af[(size_t)ga * 1024 + k0 + kg * 8];
        float4 a0 = *(const float4*)src;
        float4 a1 = *(const float4*)(src + 4);
        ushort8 u = { f2bf(a0.x), f2bf(a0.y), f2bf(a0.z), f2bf(a0.w),
                      f2bf(a1.x), f2bf(a1.y), f2bf(a1.z), f2bf(a1.w) };
        *(ushort8*)&As[row * 32 + kg * 8] = u;
      }
    } else {
      const ushort* Ab = (const ushort*)Ap;
      #pragma unroll
      for (int j = 0; j < 2; ++j) {
        int n = w * 2 + j;
        int r = n * 16 + sr;
        int ga = min(m0 + r, M - 1);
        ASYNC16(&Ab[(size_t)ga * 1024 + k0 + sc], &As[n * 512]);
      }
    }
    __syncthreads();
    bf16x8 af[4], bfr[4];
    #pragma unroll
    for (int i = 0; i < 4; ++i)
      af[i] = *(const bf16x8*)&As[(wm * 64 + i * 16 + m15) * 32 + q4 * 8];
    #pragma unroll
    for (int i = 0; i < 4; ++i)
      bfr[i] = *(const bf16x8*)&Bs[(wn * 64 + i * 16 + m15) * 32 + q4 * 8];
    #pragma unroll
    for (int i = 0; i < 4; ++i)
      #pragma unroll
      for (int j = 0; j < 4; ++j)
        acc[i][j] = __builtin_amdgcn_mfma_f32_16x16x32_bf16(af[i], bfr[j],
                                                            acc[i][j], 0, 0, 0);
  }
  #pragma unroll
  for (int j = 0; j < 4; ++j) {
    int col = n0 + wn * 64 + j * 16 + m15;
    float bb = bias ? bias[col] : 0.f;
    #pragma unroll
    for (int i = 0; i < 4; ++i) {
      #pragma unroll
      for (int r = 0; r < 4; ++r) {
        int row = m0 + wm * 64 + i * 16 + q4 * 4 + r;
        if (row < M) {
          float v = (acc[i][j][r] + bb) * scale;
          if constexpr (C_F32)
            ((float*)Cp)[(size_t)row * 1024 + col] = v;
          else
            ((ushort*)Cp)[(size_t)row * 1024 + col] = f2bf(v);
        }
      }
    }
  }
}

// ---------- fused K|V GEMM: Bt = [Wk^T ; Wv^T], N=2048, split epilogue ----
__global__ __launch_bounds__(256) void gemm_kv(
    const ushort* __restrict__ Ab, const ushort* __restrict__ Bt,
    const float* __restrict__ bv, ushort* __restrict__ k_s,
    ushort* __restrict__ v_s, int M, float sck) {
  __shared__ ushort As[128 * 32];
  __shared__ ushort Bs[128 * 32];
  const int tid  = threadIdx.x;
  const int lane = tid & 63, w = tid >> 6;
  const int m15  = lane & 15, q4 = lane >> 4;
  const int wm   = w >> 1,  wn = w & 1;
  const int m0 = blockIdx.x * 128, n0 = blockIdx.y * 128;   // n0 0..1920
  const int sr = lane >> 2;
  const int sc = (lane & 3) * 8;
  f32x4 acc[4][4] = {};
  for (int k0 = 0; k0 < 1024; k0 += 32) {
    __syncthreads();
    #pragma unroll
    for (int j = 0; j < 2; ++j) {
      int n = w * 2 + j;
      int r = n * 16 + sr;
      ASYNC16(&Bt[(size_t)(n0 + r) * 1024 + k0 + sc], &Bs[n * 512]);
    }
    #pragma unroll
    for (int j = 0; j < 2; ++j) {
      int n = w * 2 + j;
      int r = n * 16 + sr;
      int ga = min(m0 + r, M - 1);
      ASYNC16(&Ab[(size_t)ga * 1024 + k0 + sc], &As[n * 512]);
    }
    __syncthreads();
    bf16x8 af[4], bfr[4];
    #pragma unroll
    for (int i = 0; i < 4; ++i)
      af[i] = *(const bf16x8*)&As[(wm * 64 + i * 16 + m15) * 32 + q4 * 8];
    #pragma unroll
    for (int i = 0; i < 4; ++i)
      bfr[i] = *(const bf16x8*)&Bs[(wn * 64 + i * 16 + m15) * 32 + q4 * 8];
    #pragma unroll
    for (int i = 0; i < 4; ++i)
      #pragma unroll
      for (int j = 0; j < 4; ++j)
        acc[i][j] = __builtin_amdgcn_mfma_f32_16x16x32_bf16(af[i], bfr[j],
                                                            acc[i][j], 0, 0, 0);
  }
  const bool isv = n0 >= 1024;          // uniform per block
  ushort* C = isv ? v_s : k_s;
  const int nb = isv ? n0 - 1024 : n0;
  const float scale = isv ? 1.0f : sck;
  #pragma unroll
  for (int j = 0; j < 4; ++j) {
    int col = nb + wn * 64 + j * 16 + m15;
    float bb = isv ? bv[col] : 0.f;
    #pragma unroll
    for (int i = 0; i < 4; ++i) {
      #pragma unroll
      for (int r = 0; r < 4; ++r) {
        int row = m0 + wm * 64 + i * 16 + q4 * 4 + r;
        if (row < M)
          C[(size_t)row * 1024 + col] = f2bf((acc[i][j][r] + bb) * scale);
      }
    }
  }
}

// ---------- fused attention ----------
// KVBLK=128, double-buffered K tile, raw-barrier pipeline (no vmcnt drain):
// K-prefetch for chunk t+1 is issued FIRST (order pinned); the V register
// loads issued later and consumed by PV force (in-order vmcnt) all older
// K-prefetches complete before each wave reaches the end-of-chunk barrier.
__global__ __launch_bounds__(256) void attn(
    const ushort* __restrict__ q_s, const ushort* __restrict__ k_s,
    const ushort* __restrict__ v_t, float* __restrict__ qk_out,
    ushort* __restrict__ wv) {
  __shared__ ushort Kb[2 * 128 * 64];   // 2 x 16 KB, XOR-swizzled columns
  __shared__ ushort Pw[4][16 * 136];    // per-wave P tile [16][128] pad 136
  const int tid  = threadIdx.x;
  const int lane = tid & 63, w = tid >> 6;
  const int m15  = lane & 15, q4 = lane >> 4;
  const int h = blockIdx.y, b = blockIdx.z;
  const int trow = blockIdx.x * 64 + w * 16;
  const ushort* qrow = &q_s[(size_t)(b * 448 + trow + m15) * 1024 + h * 64];
  bf16x8 qf0 = *(const bf16x8*)&qrow[q4 * 8];
  bf16x8 qf1 = *(const bf16x8*)&qrow[32 + q4 * 8];
  f32x4 o[4] = {};
  float m_r[4] = {SINF, SINF, SINF, SINF};
  float l_r[4] = {0.f, 0.f, 0.f, 0.f};
  const int krb = lane >> 3;                       // staging row-in-slab 0..7
  const int kc_sw = ((lane & 7) ^ krb) * 8;        // pre-swizzled source col
  const ushort* kbase = &k_s[(size_t)(b * 1500) * 1024 + h * 64 + kc_sw];
  const ushort* vbase = &v_t[((size_t)(b * 16 + h) * 64 + m15) * 1600 + q4 * 8];

  // prologue: stage chunk 0 into Kb[0], full drain once
  #pragma unroll
  for (int j = 0; j < 4; ++j) {
    int n = w * 4 + j;                  // slab 0..15 (8 rows each)
    int sg = min(n * 8 + krb, 1499);
    ASYNC16(&kbase[(size_t)sg * 1024], &Kb[n * 512]);
  }
  __syncthreads();

  for (int t = 0; t < 12; ++t) {
    const int s0 = t * 128;
    const ushort* Kc = &Kb[(t & 1) * (128 * 64)];
    // --- pinned-first prefetch of chunk t+1 into the other buffer ---
    if (t + 1 < 12) {
      __builtin_amdgcn_sched_barrier(0);
      ushort* Kn = (ushort*)&Kb[((t + 1) & 1) * (128 * 64)];
      #pragma unroll
      for (int j = 0; j < 4; ++j) {
        int n = w * 4 + j;
        int sg = min(s0 + 128 + n * 8 + krb, 1499);
        ASYNC16(&kbase[(size_t)sg * 1024], &Kn[n * 512]);
      }
      __builtin_amdgcn_sched_barrier(0);
    }
    // --- QK^T: 8 s-col tiles, swizzled reads (2-way per 16-lane phase) ---
    f32x4 lg[8];
    #pragma unroll
    for (int scol = 0; scol < 8; ++scol) {
      const int r = scol * 16 + m15;
      const int sw = (m15 & 7) * 8;     // == (r&7)*8
      bf16x8 kf0 = *(const bf16x8*)&Kc[r * 64 + ((q4 * 8) ^ sw)];
      bf16x8 kf1 = *(const bf16x8*)&Kc[r * 64 + ((32 + q4 * 8) ^ sw)];
      f32x4 a = {};
      a = __builtin_amdgcn_mfma_f32_16x16x32_bf16(qf0, kf0, a, 0, 0, 0);
      a = __builtin_amdgcn_mfma_f32_16x16x32_bf16(qf1, kf1, a, 0, 0, 0);
      lg[scol] = a;
    }
    // --- chunk row-max ---
    float mc[4] = {SINF, SINF, SINF, SINF};
    #pragma unroll
    for (int scol = 0; scol < 8; ++scol) {
      bool valid = (s0 + scol * 16 + m15) < 1500;
      #pragma unroll
      for (int r = 0; r < 4; ++r)
        mc[r] = fmaxf(mc[r], valid ? lg[scol][r] : SINF);
    }
    #pragma unroll
    for (int off = 1; off < 16; off <<= 1)
      #pragma unroll
      for (int r = 0; r < 4; ++r)
        mc[r] = fmaxf(mc[r], __shfl_xor(mc[r], off));
    // --- online-softmax rescale ---
    #pragma unroll
    for (int r = 0; r < 4; ++r) {
      float mn = fmaxf(m_r[r], mc[r]);
      float alpha = __expf(m_r[r] - mn);
      l_r[r] *= alpha;
      #pragma unroll
      for (int d = 0; d < 4; ++d) o[d][r] *= alpha;
      m_r[r] = mn;
    }
    // --- P = exp(l - m), nontemporal qk store, row-sum ---
    float psum[4] = {0.f, 0.f, 0.f, 0.f};
    #pragma unroll
    for (int scol = 0; scol < 8; ++scol) {
      int sg = s0 + scol * 16 + m15;
      bool valid = sg < 1500;
      #pragma unroll
      for (int r = 0; r < 4; ++r) {
        float lv = lg[scol][r];
        float p = valid ? __expf(lv - m_r[r]) : 0.f;
        psum[r] += p;
        Pw[w][(q4 * 4 + r) * 136 + scol * 16 + m15] = f2bf(p);
        if (valid)
          __builtin_nontemporal_store(
              lv, &qk_out[(size_t)((b * 16 + h) * 448 + trow + q4 * 4 + r)
                              * 1500 + sg]);
      }
    }
    #pragma unroll
    for (int off = 1; off < 16; off <<= 1)
      #pragma unroll
      for (int r = 0; r < 4; ++r)
        psum[r] += __shfl_xor(psum[r], off);
    #pragma unroll
    for (int r = 0; r < 4; ++r) l_r[r] += psum[r];
    // --- PV: 4 k-steps; V fragments from global (L2/L3-resident) ---
    #pragma unroll
    for (int ks = 0; ks < 4; ++ks) {
      bf16x8 vf[4];
      #pragma unroll
      for (int d = 0; d < 4; ++d)
        vf[d] = *(const bf16x8*)&vbase[(size_t)(d * 16) * 1600 + s0 + ks * 32];
      bf16x8 pf = *(const bf16x8*)&Pw[w][m15 * 136 + ks * 32 + q4 * 8];
      #pragma unroll
      for (int d = 0; d < 4; ++d)
        o[d] = __builtin_amdgcn_mfma_f32_16x16x32_bf16(pf, vf[d], o[d], 0, 0, 0);
    }
    // --- raw barrier, no vmcnt drain (prefetches stay in flight) ---
    __builtin_amdgcn_sched_barrier(0);
    __builtin_amdgcn_s_barrier();
    __builtin_amdgcn_sched_barrier(0);
  }
  // normalize + store wv
  #pragma unroll
  for (int d = 0; d < 4; ++d)
    #pragma unroll
    for (int r = 0; r < 4; ++r) {
      float val = o[d][r] / l_r[r];
      wv[(size_t)(b * 448 + trow + q4 * 4 + r) * 1024 + h * 64 + d * 16 + m15]
          = f2bf(val);
    }
}

// ---------- launch ----------
extern "C" void kernel_launch(void* const* d_in, const int* in_sizes, int n_in,
                              void* d_out, int out_size, void* d_ws,
                              size_t ws_size, hipStream_t stream) {
  const float* x  = (const float*)d_in[0];   // [8,448,1024] f32
  const float* xa = (const float*)d_in[1];   // [8,1500,1024] f32
  const float* Wq = (const float*)d_in[2];
  const float* bq = (const float*)d_in[3];
  const float* Wk = (const float*)d_in[4];
  const float* Wv = (const float*)d_in[5];
  const float* bv = (const float*)d_in[6];
  const float* Wo = (const float*)d_in[7];
  const float* bo = (const float*)d_in[8];
  float* out = (float*)d_out;                        // [8,448,1024] f32
  float* qk  = out + (size_t)8 * 448 * 1024;         // [8,16,448,1500] f32
  char* ws = (char*)d_ws;
  ushort* Wt    = (ushort*)ws;                               // 4x 1M bf16 (8 MB)
  ushort* q_s   = (ushort*)(ws + (size_t)8   * 1024 * 1024); // 3584x1024 bf16
  ushort* k_s   = (ushort*)(ws + (size_t)16  * 1024 * 1024); // 12000x1024 bf16
  ushort* v_s   = (ushort*)(ws + (size_t)42  * 1024 * 1024); // 12000x1024 bf16
  ushort* wv_s  = (ushort*)(ws + (size_t)68  * 1024 * 1024); // 3584x1024 bf16
  ushort* xa_bf = (ushort*)(ws + (size_t)84  * 1024 * 1024); // 12000x1024 bf16
  ushort* v_t   = (ushort*)(ws + (size_t)112 * 1024 * 1024); // 128x64x1600 bf16

  to_bf16<<<dim3(2048), 256, 0, stream>>>(xa, xa_bf, 1536000);
  transpose_w<<<dim3(32, 32, 4), 256, 0, stream>>>(Wq, Wk, Wv, Wo, Wt);
  const float sc = 0.35355339059327373f;  // 64^-0.25
  gemm_bt<true, false><<<dim3(28, 8), 256, 0, stream>>>(x, Wt, bq, q_s, 3584, sc);
  gemm_kv<<<dim3(94, 16), 256, 0, stream>>>(xa_bf, Wt + 1u * 1048576u, bv,
                                            k_s, v_s, 12000, sc);
  transpose_v<<<dim3(50, 2, 128), 256, 0, stream>>>(v_s, v_t);
  attn<<<dim3(7, 16, 8), 256, 0, stream>>>(q_s, k_s, v_t, qk, wv_s);
  gemm_bt<false, true><<<dim3(28, 8), 256, 0, stream>>>(wv_s, Wt + 3u * 1048576u,
                                                        bo, out, 3584, 1.0f);
}